// Round 6
// baseline (560.954 us; speedup 1.0000x reference)
//
#include <hip/hip_runtime.h>
#include <hip/hip_bf16.h>

// Problem constants: B=64, T=2048, D=256, U=256 (fp32 in/out)
#define BB 64
#define TT 2048
#define DD 256
#define UU 256
#define MM (BB*TT)          // 131072 GEMM rows
#define NN (3*UU)           // 768 fused output cols (z,r,h)
#define PLANE ((size_t)BB*TT*UU)   // 33554432 elements per projection plane

typedef _Float16 half8 __attribute__((ext_vector_type(8)));
typedef _Float16 half4 __attribute__((ext_vector_type(4)));
typedef float floatx4 __attribute__((ext_vector_type(4)));

// ---------------- fast math helpers ----------------
__device__ inline float fexp2(float x){
#if __has_builtin(__builtin_amdgcn_exp2f)
  return __builtin_amdgcn_exp2f(x);
#else
  return exp2f(x);
#endif
}
__device__ inline float frcp(float x){
#if __has_builtin(__builtin_amdgcn_rcpf)
  return __builtin_amdgcn_rcpf(x);
#else
  return 1.0f/x;
#endif
}

// ---------------- kernel 0a: weights -> fused transposed f16 [N=768][K=256] ----------------
__global__ __launch_bounds__(256) void prep_kernel(const float* __restrict__ kz,
                                                   const float* __restrict__ kr,
                                                   const float* __restrict__ kh,
                                                   _Float16* __restrict__ K16T){
  int o = blockIdx.x*256 + threadIdx.x;     // 0..196607
  int n = o >> 8;                            // fused col: p*256+u
  int k = o & 255;                           // d
  int p = n >> 8;
  int u = n & 255;
  const float* w = (p==0) ? kz : ((p==1) ? kr : kh);
  K16T[o] = (_Float16)w[k*UU + u];
}

// ---------------- kernel 0b: X fp32 -> f16 prepass (into d_out used as scratch) ----------------
__global__ __launch_bounds__(256) void xcvt_kernel(const float* __restrict__ X,
                                                   _Float16* __restrict__ X16){
  const size_t t = (size_t)blockIdx.x*256 + threadIdx.x;   // 1,048,576 threads
  #pragma unroll
  for (int i = 0; i < 8; i++){
    const size_t u = ((size_t)i << 20) + t;  // 16B units, lane-consecutive
    floatx4 v = *(const floatx4*)(X + u*4);
    half4 hv;
    #pragma unroll
    for (int q = 0; q < 4; q++) hv[q] = (_Float16)v[q];
    *(half4*)(X16 + u*4) = hv;
  }
}

// ---------------- kernel 1: GEMM  -> P[p][b*U+u][t] (t-major, f16, PRESCALED) ----------------
// P planes carry the scan's exp2 arguments pre-scaled:
//   Pz = -log2e   * (xz + bz)     (sigmoid arg)
//   Pr = 2*log2e  * (xr + br)     (tanh arg, doubled for exp2 form)
//   Ph = 2*log2e  * (xh + bh)
// This removes all three per-step muls from the scan's serial dependency chain.
#define BM 128
#define BN 128
#define BK 32
// T3 minimal 2-phase: double-buffered 32KB LDS, ONE barrier per K-iter (8 vs 16),
// next tile's 4 global_load_lds issued before the current tile's ds_read+MFMA so
// load latency overlaps compute. (Round-1 dbuf failed with the fp32-A path:
// VGPR 88 + 36.9KB LDS; now pure gload_lds keeps VGPR ~60 and LDS at 32KB.)
__global__ __launch_bounds__(256) void gemm_kernel(const _Float16* __restrict__ X16,
                                                   const _Float16* __restrict__ K16T,
                                                   const float* __restrict__ bz,
                                                   const float* __restrict__ br,
                                                   const float* __restrict__ bh,
                                                   _Float16* __restrict__ P){
  __shared__ __align__(16) _Float16 As[2][BM*BK];   // 2 x 8192 B
  __shared__ __align__(16) _Float16 Bs[2][BN*BK];   // 2 x 8192 B
  const int tid = threadIdx.x;

  // ---- bijective XCD-aware remap (6144 blocks = 8 XCDs x 768) ----
  const int l   = blockIdx.y*6 + blockIdx.x;   // hw linear id (x fastest)
  const int xcd = l & 7;
  const int idx = l >> 3;                      // 0..767 within xcd
  const int pnl = idx / 6;                     // 0..127: M panel within chunk
  const int by  = xcd*128 + pnl;               // logical M tile
  const int bx  = idx - pnl*6;                 // logical N tile 0..5
  const int rowBase = by*BM;
  const int nBase   = bx*BN;

  const int wave = tid >> 6, lane = tid & 63;
  const int wm = wave & 1, wn = wave >> 1;     // 2x2 wave grid, each 64x64
  const int lrow = lane & 15, lkq = lane >> 4; // frag row / k-octet

  floatx4 acc[4][4] = {};

  // Staging: chunk c = (row = c>>2, k-octet = c&3); thread owns c=tid, c=tid+256.
  const _Float16* aSrc0 = X16 + (size_t)(rowBase + (tid >> 2))*DD + (tid & 3)*8;
  const _Float16* aSrc1 = aSrc0 + (size_t)64*DD;
  const _Float16* bSrc0 = K16T + (size_t)(nBase + (tid >> 2))*DD + (tid & 3)*8;
  const _Float16* bSrc1 = bSrc0 + (size_t)64*DD;

#define STAGE(buf, k0) do { \
    __builtin_amdgcn_global_load_lds( \
        (const __attribute__((address_space(1))) void*)(aSrc0 + (k0)), \
        (__attribute__((address_space(3))) void*)(&As[(buf)][tid*8]), 16, 0, 0); \
    __builtin_amdgcn_global_load_lds( \
        (const __attribute__((address_space(1))) void*)(aSrc1 + (k0)), \
        (__attribute__((address_space(3))) void*)(&As[(buf)][2048 + tid*8]), 16, 0, 0); \
    __builtin_amdgcn_global_load_lds( \
        (const __attribute__((address_space(1))) void*)(bSrc0 + (k0)), \
        (__attribute__((address_space(3))) void*)(&Bs[(buf)][tid*8]), 16, 0, 0); \
    __builtin_amdgcn_global_load_lds( \
        (const __attribute__((address_space(1))) void*)(bSrc1 + (k0)), \
        (__attribute__((address_space(3))) void*)(&Bs[(buf)][2048 + tid*8]), 16, 0, 0); \
  } while(0)

  STAGE(0, 0);
  __syncthreads();                 // prologue drain: tile 0 resident

  #pragma unroll
  for (int kk = 0; kk < 8; kk++){
    const int cur = kk & 1;
    if (kk < 7) STAGE(cur ^ 1, (kk + 1)*BK);   // next tile in flight over compute
    half8 af[4], bf[4];
    #pragma unroll
    for (int i = 0; i < 4; i++)
      af[i] = *(const half8*)&As[cur][(wm*64 + i*16 + lrow)*BK + lkq*8];
    #pragma unroll
    for (int j = 0; j < 4; j++)
      bf[j] = *(const half8*)&Bs[cur][(wn*64 + j*16 + lrow)*BK + lkq*8];
    #pragma unroll
    for (int i = 0; i < 4; i++)
      #pragma unroll
      for (int j = 0; j < 4; j++)
        acc[i][j] = __builtin_amdgcn_mfma_f32_16x16x32_f16(af[i], bf[j], acc[i][j], 0, 0, 0);
    __syncthreads();               // single barrier/iter: drains vmcnt+lgkmcnt, flips buffers
  }
#undef STAGE

  // --- epilogue: add bias, apply plane prescale, packed half4 store ---
  const int p = bx >> 1;                // plane (z/r/h); BN=128 never crosses planes
  const int ub = (bx & 1) * 128;        // u base within plane
  const float* bias = (p==0) ? bz : ((p==1) ? br : bh);
  const float pscale = (p==0) ? -1.4426950408889634f : 2.8853900817779268f;
  _Float16* Pp = P + (size_t)p * PLANE;
  const int bidx = rowBase >> 11;                 // batch index (uniform per block)
  const int t0 = (rowBase & 2047) + wm*64 + lkq*4;
  #pragma unroll
  for (int j = 0; j < 4; j++){
    int col = ub + wn*64 + j*16 + lrow;           // u  (C/D: col = lane&15)
    float bv = bias[col];
    _Float16* rowp = Pp + (size_t)(bidx*UU + col)*TT + t0;
    #pragma unroll
    for (int i = 0; i < 4; i++){
      half4 v;
      #pragma unroll
      for (int r = 0; r < 4; r++)
        v[r] = (_Float16)((acc[i][j][r] + bv) * pscale);
      *(half4*)(rowp + i*16) = v;
    }
  }
}

// ---------------- kernel 2: time scan, ILP-2 (two chains per lane) ----------------
// 2048-step serial chain per (b,u): ~104cy dependent latency + ~45cy issue per step
// measured 146cy/step at 1 chain/lane. Two independent chains interleave to fill
// each other's stalls. Round-4 failure root cause: __launch_bounds__(64) let the
// compiler target 60 VGPRs -> the register ring spilled -> chains serialized.
// Fix: __launch_bounds__(64, 1) (1 wave/EU -> up to 512 VGPRs), ring = 24 half8.
// Prescaled P (see gemm) removes the 3 muls from the chain:
//   z  = rcp(1+exp2(Pz + h*mz2)),          mz2 = -log2e*mz
//   w  = rcp(1+exp2(Pr + h*mr2)),          mr2 = 2log2e*mr;  r2 = 4log2e*(1-w)
//   hh = 1 - 2*rcp(1+exp2(Ph + r2*h))
//   h' = hh + z*(h-hh)            (== (1-z)*hh + z*h)
#define PF 8           // timesteps per chunk (1 half8 per plane per chain)
#define NBUF 4         // ring depth: NC=256 % 4 == 0; prefetch distance 3 chunks
__global__ __launch_bounds__(64, 1) void scan_kernel(const _Float16* __restrict__ P,
                                                     const float* __restrict__ mz,
                                                     const float* __restrict__ mr,
                                                     float* __restrict__ out){
  const int lid = threadIdx.x;
  const int g   = blockIdx.x;                 // 0..127
  const int c0  = g*128 + lid;                // chain A
  const int c1  = c0 + 64;                    // chain B (same batch row)
  const int b   = c0 >> 8;
  const int u0  = c0 & 255;
  const int u1  = u0 + 64;
  const half8* pz0 = (const half8*)(P + (size_t)c0*TT);
  const half8* pr0 = (const half8*)(P + PLANE + (size_t)c0*TT);
  const half8* ph0 = (const half8*)(P + 2*PLANE + (size_t)c0*TT);
  const half8* pz1 = (const half8*)(P + (size_t)c1*TT);
  const half8* pr1 = (const half8*)(P + PLANE + (size_t)c1*TT);
  const half8* ph1 = (const half8*)(P + 2*PLANE + (size_t)c1*TT);
  float* po0 = out + (size_t)b*(TT*UU) + u0;
  float* po1 = po0 + 64;
  const float L2E    = 1.4426950408889634f;
  const float F4L2E  = 5.7707801635558536f;   // 4*log2(e)
  const float mz0s = -L2E*mz[u0], mr0s = 2.0f*L2E*mr[u0];
  const float mz1s = -L2E*mz[u1], mr1s = 2.0f*L2E*mr[u1];
  float h0 = 0.0f, h1 = 0.0f;

  half8 qz[NBUF][2], qr[NBUF][2], qh[NBUF][2];   // [buf][chain], all static-indexed

#define LOADC(buf, c) do { \
    qz[buf][0] = pz0[c]; qr[buf][0] = pr0[c]; qh[buf][0] = ph0[c]; \
    qz[buf][1] = pz1[c]; qr[buf][1] = pr1[c]; qh[buf][1] = ph1[c]; \
  } while(0)

#define PROC(buf, c) do { \
    _Pragma("unroll") \
    for (int i = 0; i < PF; i++){ \
      float az0 = fmaf(h0, mz0s, (float)qz[buf][0][i]); \
      float ar0 = fmaf(h0, mr0s, (float)qr[buf][0][i]); \
      float az1 = fmaf(h1, mz1s, (float)qz[buf][1][i]); \
      float ar1 = fmaf(h1, mr1s, (float)qr[buf][1][i]); \
      float z0 = frcp(1.0f + fexp2(az0)); \
      float z1 = frcp(1.0f + fexp2(az1)); \
      float w0 = frcp(1.0f + fexp2(ar0)); \
      float w1 = frcp(1.0f + fexp2(ar1)); \
      float r20 = fmaf(w0, -F4L2E, F4L2E); \
      float r21 = fmaf(w1, -F4L2E, F4L2E); \
      float ah0 = fmaf(r20, h0, (float)qh[buf][0][i]); \
      float ah1 = fmaf(r21, h1, (float)qh[buf][1][i]); \
      float v0 = frcp(1.0f + fexp2(ah0)); \
      float v1 = frcp(1.0f + fexp2(ah1)); \
      float hh0 = fmaf(v0, -2.0f, 1.0f); \
      float hh1 = fmaf(v1, -2.0f, 1.0f); \
      h0 = fmaf(z0, h0 - hh0, hh0); \
      h1 = fmaf(z1, h1 - hh1, hh1); \
      po0[(size_t)((c)*PF + i)*UU] = h0; \
      po1[(size_t)((c)*PF + i)*UU] = h1; \
    } \
    if ((c) + NBUF < NC) LOADC(buf, (c) + NBUF); \
  } while(0)

  const int NC = TT/PF;   // 256 chunks
  LOADC(0, 0); LOADC(1, 1); LOADC(2, 2); LOADC(3, 3);
  for (int c = 0; c < NC; c += NBUF){
    PROC(0, c);
    PROC(1, c+1);
    PROC(2, c+2);
    PROC(3, c+3);
  }
#undef LOADC
#undef PROC
}

extern "C" void kernel_launch(void* const* d_in, const int* in_sizes, int n_in,
                              void* d_out, int out_size, void* d_ws, size_t ws_size,
                              hipStream_t stream) {
  (void)in_sizes; (void)n_in; (void)out_size; (void)ws_size;
  const float* x  = (const float*)d_in[0];
  const float* kz = (const float*)d_in[1];
  const float* kr = (const float*)d_in[2];
  const float* kh = (const float*)d_in[3];
  const float* mz = (const float*)d_in[4];
  const float* mr = (const float*)d_in[5];
  const float* bz = (const float*)d_in[6];
  const float* br = (const float*)d_in[7];
  const float* bh = (const float*)d_in[8];
  float* out = (float*)d_out;

  // ws layout: [K16T: 768*256 f16 = 393216 B][P: 3 planes * 33554432 f16 = 201326592 B]
  _Float16* K16T = (_Float16*)d_ws;
  _Float16* P    = (_Float16*)((char*)d_ws + 393216);
  // X16 (67MB) lives in d_out (134MB): gemm reads it, then scan fully overwrites out.
  _Float16* X16  = (_Float16*)d_out;

  hipLaunchKernelGGL(xcvt_kernel, dim3(4096), dim3(256), 0, stream, x, X16);
  hipLaunchKernelGGL(prep_kernel, dim3(NN*DD/256), dim3(256), 0, stream, kz, kr, kh, K16T);
  hipLaunchKernelGGL(gemm_kernel, dim3(NN/BN, MM/BM), dim3(256), 0, stream,
                     X16, K16T, bz, br, bh, P);
  hipLaunchKernelGGL(scan_kernel, dim3(128), dim3(64), 0, stream, P, mz, mr, out);
}